// Round 2
// baseline (348.593 us; speedup 1.0000x reference)
//
#include <hip/hip_runtime.h>
#include <hip/hip_bf16.h>
#include <math.h>

typedef __attribute__((ext_vector_type(8))) short bf8;
typedef __attribute__((ext_vector_type(4))) float f4;

__device__ __forceinline__ ushort f2bf(float x){
  union { float f; unsigned u; } v; v.f = x;
  unsigned r = (v.u + 0x7fffu + ((v.u >> 16) & 1u)) >> 16;
  return (ushort)r;
}
__device__ __forceinline__ float bf2f(ushort b){
  union { unsigned u; float f; } v; v.u = ((unsigned)b) << 16;
  return v.f;
}

// ---------------- generic 64x64 tile bf16 MFMA GEMM ----------------
struct GP {
  const ushort* A; long lda; long aBatch; long aHead;
  const ushort* Bt; long ldb; long bBatch; long bHead;
  const ushort* Bt2;
  int K; int zdiv;
  float* outf; ushort* outb;
  ushort* o1; ushort* o2; ushort* o3;
  const float* bias0; const float* bias1; const float* bias2; const float* bias3;
  const float* geom; const float* wg; const float* bgv; const int* mask;
  const float* addf;
};

enum { EP_QKVG=0, EP_SCORES, EP_CTX, EP_GCN, EP_ATTNOUT, EP_FF, EP_FINAL };

template<int EPI, bool DUAL>
__global__ __launch_bounds__(256)
void gemm_k(GP p) {
  __shared__ __align__(16) ushort As[64*64];
  __shared__ __align__(16) ushort Bs[64*64];
  __shared__ __align__(16) ushort Bs2[DUAL ? 64*64 : 8];
  const int tid = threadIdx.x;
  const int lane = tid & 63, wave = tid >> 6;
  const int wm = wave >> 1, wn = wave & 1;
  const int bm = blockIdx.x, bn = blockIdx.y, z = blockIdx.z;
  const int zb = z / p.zdiv, zh = z % p.zdiv;
  const ushort* Ab  = p.A  + (long)zb*p.aBatch + (long)zh*p.aHead + (long)bm*64*p.lda;
  const ushort* Btb = p.Bt + (long)zb*p.bBatch + (long)zh*p.bHead + (long)bn*64*p.ldb;
  const ushort* Bt2b = DUAL ? (p.Bt2 + (long)bn*64*p.ldb) : (const ushort*)nullptr;

  f4 acc[2][2] = {};
  f4 acc2[2][2] = {};

  const int sr = tid >> 3, sc = tid & 7;
  const int g = lane >> 4, lr = lane & 15;

  for (int k0 = 0; k0 < p.K; k0 += 64) {
    #pragma unroll
    for (int i = 0; i < 2; ++i) {
      int row = sr + i*32;
      int sw = (sc ^ (row & 7)) * 8;
      *(uint4*)&As[row*64 + sw] = *(const uint4*)(Ab  + (long)row*p.lda + k0 + sc*8);
      *(uint4*)&Bs[row*64 + sw] = *(const uint4*)(Btb + (long)row*p.ldb + k0 + sc*8);
      if (DUAL)
        *(uint4*)&Bs2[row*64 + sw] = *(const uint4*)(Bt2b + (long)row*p.ldb + k0 + sc*8);
    }
    __syncthreads();
    #pragma unroll
    for (int kw = 0; kw < 2; ++kw) {
      bf8 af[2], bfr[2], bf2[2];
      int chunk = kw*4 + g;
      #pragma unroll
      for (int f = 0; f < 2; ++f) {
        int ar = wm*32 + f*16 + lr;
        af[f]  = *(const bf8*)&As[ar*64 + ((chunk ^ (ar & 7)) * 8)];
        int br = wn*32 + f*16 + lr;
        bfr[f] = *(const bf8*)&Bs[br*64 + ((chunk ^ (br & 7)) * 8)];
        if (DUAL) bf2[f] = *(const bf8*)&Bs2[br*64 + ((chunk ^ (br & 7)) * 8)];
      }
      #pragma unroll
      for (int fm = 0; fm < 2; ++fm)
        #pragma unroll
        for (int fn = 0; fn < 2; ++fn) {
          acc[fm][fn] = __builtin_amdgcn_mfma_f32_16x16x32_bf16(af[fm], bfr[fn], acc[fm][fn], 0,0,0);
          if (DUAL) acc2[fm][fn] = __builtin_amdgcn_mfma_f32_16x16x32_bf16(af[fm], bf2[fn], acc2[fm][fn], 0,0,0);
        }
    }
    __syncthreads();
  }

  #pragma unroll
  for (int fm = 0; fm < 2; ++fm)
  #pragma unroll
  for (int fn = 0; fn < 2; ++fn)
  #pragma unroll
  for (int i = 0; i < 4; ++i) {
    int grow = bm*64 + wm*32 + fm*16 + g*4 + i;
    int gcol = bn*64 + wn*32 + fn*16 + lr;
    float v = acc[fm][fn][i];
    if constexpr (EPI == EP_QKVG) {
      int sec = gcol >> 9, cc = gcol & 511;
      const float* bp = sec==0 ? p.bias0 : sec==1 ? p.bias1 : sec==2 ? p.bias2 : p.bias3;
      v += bp[cc];
      ushort bvv = f2bf(v);
      if (sec == 0)      p.outb[(long)grow*512 + cc] = bvv;
      else if (sec == 1) p.o1[(long)grow*512 + cc] = bvv;
      else {
        int b = grow / 768, l = grow - b*768;
        ushort* dst = (sec==2) ? p.o2 : p.o3;
        dst[((long)b*512 + cc)*768 + l] = bvv;
      }
    } else if constexpr (EPI == EP_SCORES) {
      int b = z >> 3, h = z & 7;
      float bias = p.bgv[h];
      long gidx = (((long)b*768 + grow)*768 + gcol)*7;
      #pragma unroll
      for (int q = 0; q < 7; ++q) bias += p.geom[gidx+q] * p.wg[q*8 + h];
      float s = (p.mask[b*768 + gcol] == 0) ? -10000.f : (v*0.125f + bias);
      p.outb[((long)z*768 + grow)*768 + gcol] = f2bf(s);
    } else if constexpr (EPI == EP_CTX) {
      int b = z >> 3, h = z & 7;
      p.outb[((long)(b*768 + grow))*512 + h*64 + gcol] = f2bf(v);
    } else if constexpr (EPI == EP_GCN) {
      float ge = 0.5f * v * (1.f + erff(v * 0.70710678118f));
      p.outf[((long)z*768 + grow)*512 + gcol] = ge;
    } else if constexpr (EPI == EP_ATTNOUT) {
      p.outf[(long)grow*512 + gcol] = v + p.bias0[gcol];
    } else if constexpr (EPI == EP_FF) {
      float u = v + p.bias0[gcol];
      float gt = acc2[fm][fn][i] + p.bias0[2048 + gcol];
      float a = u / (1.f + expf(-gt));
      p.outb[(long)grow*2048 + gcol] = f2bf(a);
    } else if constexpr (EPI == EP_FINAL) {
      long idx = (long)grow*512 + gcol;
      p.outf[idx] = p.addf[idx] + v + p.bias0[gcol];
    }
  }
}

// ---------------- transpose + fp32->bf16 convert: dst[C][R] = src[R][C] ----------------
__global__ __launch_bounds__(256) void transpose_bf(const float* src, ushort* dst, int R, int C) {
  __shared__ float t[32][33];
  int r0 = blockIdx.x*32, c0 = blockIdx.y*32;
  int tr = threadIdx.x >> 5, tc = threadIdx.x & 31;
  #pragma unroll
  for (int i = 0; i < 4; ++i)
    t[tr + i*8][tc] = src[(long)(r0 + tr + i*8)*C + c0 + tc];
  __syncthreads();
  #pragma unroll
  for (int i = 0; i < 4; ++i)
    dst[(long)(c0 + tr + i*8)*R + r0 + tc] = f2bf(t[tc][tr + i*8]);
}

// ---------------- LayerNorm (row=512) -> bf16 ----------------
__global__ __launch_bounds__(256) void ln_k(const float* x, const float* gam, const float* bet, ushort* out) {
  int row = blockIdx.x, tid = threadIdx.x;
  long base = (long)row*512;
  float v0 = x[base+tid], v1 = x[base+tid+256];
  float s = v0+v1, q = v0*v0 + v1*v1;
  #pragma unroll
  for (int off=32; off>=1; off>>=1){ s += __shfl_down(s,off,64); q += __shfl_down(q,off,64); }
  __shared__ float red[8];
  int lane=tid&63, wave=tid>>6;
  if (lane==0){ red[wave]=s; red[4+wave]=q; }
  __syncthreads();
  if (tid==0){ red[0]=red[0]+red[1]+red[2]+red[3]; red[4]=red[4]+red[5]+red[6]+red[7]; }
  __syncthreads();
  float mu = red[0]*(1.f/512.f);
  float var = red[4]*(1.f/512.f) - mu*mu;
  float rs = rsqrtf(var + 1e-5f);
  out[base+tid]     = f2bf((v0-mu)*rs*gam[tid]     + bet[tid]);
  out[base+tid+256] = f2bf((v1-mu)*rs*gam[tid+256] + bet[tid+256]);
}

// ---------------- residual + LayerNorm2 ----------------
__global__ __launch_bounds__(256) void resid_ln2_k(const float* x, const float* ao, const float* gc,
    const float* gatep, const float* gam, const float* bet, float* xmid, ushort* h2) {
  int row = blockIdx.x, tid = threadIdx.x;
  long base = (long)row*512;
  float gate = *gatep;
  float v0 = x[base+tid]     + ao[base+tid]     + gc[base+tid]*gate;
  float v1 = x[base+tid+256] + ao[base+tid+256] + gc[base+tid+256]*gate;
  xmid[base+tid] = v0; xmid[base+tid+256] = v1;
  float s = v0+v1, q = v0*v0 + v1*v1;
  #pragma unroll
  for (int off=32; off>=1; off>>=1){ s += __shfl_down(s,off,64); q += __shfl_down(q,off,64); }
  __shared__ float red[8];
  int lane=tid&63, wave=tid>>6;
  if (lane==0){ red[wave]=s; red[4+wave]=q; }
  __syncthreads();
  if (tid==0){ red[0]=red[0]+red[1]+red[2]+red[3]; red[4]=red[4]+red[5]+red[6]+red[7]; }
  __syncthreads();
  float mu = red[0]*(1.f/512.f);
  float var = red[4]*(1.f/512.f) - mu*mu;
  float rs = rsqrtf(var + 1e-5f);
  h2[base+tid]     = f2bf((v0-mu)*rs*gam[tid]     + bet[tid]);
  h2[base+tid+256] = f2bf((v1-mu)*rs*gam[tid+256] + bet[tid+256]);
}

// ---------------- adj: normalized exp(-g0/5) with mask -> bf16 ----------------
__global__ __launch_bounds__(256) void adj_k(const float* geom, const int* mask, ushort* adj) {
  int bl = blockIdx.x;            // b*768 + l
  int b = bl / 768;
  int tid = threadIdx.x;
  float ml = (float)mask[bl];
  float e[3]; float s = 0.f;
  #pragma unroll
  for (int j=0;j<3;j++){
    int m = tid + j*256;
    float mm = (float)mask[b*768 + m];
    e[j] = expf(-geom[((long)bl*768 + m)*7] * 0.2f) * mm;
    s += e[j];
  }
  #pragma unroll
  for (int off=32; off>=1; off>>=1) s += __shfl_down(s,off,64);
  __shared__ float red[4];
  int lane=tid&63, wave=tid>>6;
  if (lane==0) red[wave]=s;
  __syncthreads();
  if (tid==0) red[0]=red[0]+red[1]+red[2]+red[3];
  __syncthreads();
  float inv = ml / (ml*red[0] + 1e-6f);
  #pragma unroll
  for (int j=0;j<3;j++){
    int m = tid + j*256;
    adj[(long)bl*768 + m] = f2bf(e[j] * inv);
  }
}

// ---------------- in-place row softmax over bf16 (row len 768) ----------------
__global__ __launch_bounds__(256) void softmax_k(ushort* sbuf) {
  long base = (long)blockIdx.x * 768;
  int tid = threadIdx.x;
  float v[3];
  float mx = -1e30f;
  #pragma unroll
  for (int j=0;j<3;j++){ v[j] = bf2f(sbuf[base + tid + j*256]); mx = fmaxf(mx, v[j]); }
  #pragma unroll
  for (int off=32; off>=1; off>>=1) mx = fmaxf(mx, __shfl_down(mx,off,64));
  __shared__ float red[8];
  int lane=tid&63, wave=tid>>6;
  if (lane==0) red[wave]=mx;
  __syncthreads();
  if (tid==0) red[0]=fmaxf(fmaxf(red[0],red[1]),fmaxf(red[2],red[3]));
  __syncthreads();
  mx = red[0];
  float s=0.f;
  #pragma unroll
  for (int j=0;j<3;j++){ v[j] = expf(v[j]-mx); s += v[j]; }
  #pragma unroll
  for (int off=32; off>=1; off>>=1) s += __shfl_down(s,off,64);
  if (lane==0) red[4+wave]=s;
  __syncthreads();
  if (tid==0) red[4]=red[4]+red[5]+red[6]+red[7];
  __syncthreads();
  float inv = 1.f/red[4];
  #pragma unroll
  for (int j=0;j<3;j++) sbuf[base+tid+j*256] = f2bf(v[j]*inv);
}

extern "C" void kernel_launch(void* const* d_in, const int* in_sizes, int n_in,
                              void* d_out, int out_size, void* d_ws, size_t ws_size,
                              hipStream_t stream) {
  const float* x    = (const float*)d_in[0];
  const float* geom = (const float*)d_in[1];
  const int*   mask = (const int*)d_in[2];
  const float* Wq   = (const float*)d_in[3];
  const float* bq   = (const float*)d_in[4];
  const float* Wk   = (const float*)d_in[5];
  const float* bk   = (const float*)d_in[6];
  const float* Wv   = (const float*)d_in[7];
  const float* bv   = (const float*)d_in[8];
  const float* Wo   = (const float*)d_in[9];
  const float* bo   = (const float*)d_in[10];
  const float* Wg   = (const float*)d_in[11];
  const float* bg   = (const float*)d_in[12];
  const float* Wgcn = (const float*)d_in[13];
  const float* bgcn = (const float*)d_in[14];
  const float* gate = (const float*)d_in[15];
  const float* W1   = (const float*)d_in[16];
  const float* b1   = (const float*)d_in[17];
  const float* W2   = (const float*)d_in[18];
  const float* b2   = (const float*)d_in[19];
  const float* ln1s = (const float*)d_in[20];
  const float* ln1b = (const float*)d_in[21];
  const float* ln2s = (const float*)d_in[22];
  const float* ln2b = (const float*)d_in[23];
  float* out = (float*)d_out;

  char* wp = (char*)d_ws;
  auto alloc = [&](size_t bytes)->char* { char* r = wp; wp += (bytes + 255) & ~(size_t)255; return r; };
  ushort* wqkvgT = (ushort*)alloc(2048*512*2);
  ushort* woT    = (ushort*)alloc(512*512*2);
  ushort* w1T    = (ushort*)alloc(4096*512*2);
  ushort* w2T    = (ushort*)alloc(512*2048*2);
  ushort* hbf    = (ushort*)alloc(3072*512*2);
  ushort* qbf    = (ushort*)alloc(3072*512*2);
  ushort* kbf    = (ushort*)alloc(3072*512*2);
  ushort* vt     = (ushort*)alloc((size_t)4*512*768*2);
  ushort* gt     = (ushort*)alloc((size_t)4*512*768*2);
  ushort* adjb   = (ushort*)alloc((size_t)4*768*768*2);
  ushort* sbf    = (ushort*)alloc((size_t)32*768*768*2);
  ushort* ctx    = (ushort*)alloc(3072*512*2);
  float*  aout   = (float*)alloc(3072*512*4);
  float*  gcnr   = (float*)alloc(3072*512*4);
  float*  xmid   = (float*)alloc(3072*512*4);
  ushort* h2bf   = (ushort*)alloc(3072*512*2);
  ushort* act    = sbf;   // reuse (12.6MB <= 37.7MB), scores dead by then

  // weight transposes -> bf16
  transpose_bf<<<dim3(16,16), 256, 0, stream>>>(Wq,   wqkvgT + 0*512*512, 512, 512);
  transpose_bf<<<dim3(16,16), 256, 0, stream>>>(Wk,   wqkvgT + 1*512*512, 512, 512);
  transpose_bf<<<dim3(16,16), 256, 0, stream>>>(Wv,   wqkvgT + 2*512*512, 512, 512);
  transpose_bf<<<dim3(16,16), 256, 0, stream>>>(Wgcn, wqkvgT + 3*512*512, 512, 512);
  transpose_bf<<<dim3(16,16), 256, 0, stream>>>(Wo,   woT, 512, 512);
  transpose_bf<<<dim3(16,128),256, 0, stream>>>(W1,   w1T, 512, 4096);
  transpose_bf<<<dim3(64,16), 256, 0, stream>>>(W2,   w2T, 2048, 512);

  // LN1
  ln_k<<<3072, 256, 0, stream>>>(x, ln1s, ln1b, hbf);

  // adj
  adj_k<<<3072, 256, 0, stream>>>(geom, mask, adjb);

  GP p{};
  // GEMM1: h @ [Wq|Wk|Wv|Wgcn]  (M=3072,N=2048,K=512)
  p.A = hbf; p.lda = 512; p.aBatch = 0; p.aHead = 0;
  p.Bt = wqkvgT; p.ldb = 512; p.bBatch = 0; p.bHead = 0;
  p.K = 512; p.zdiv = 1;
  p.outb = qbf; p.o1 = kbf; p.o2 = vt; p.o3 = gt;
  p.bias0 = bq; p.bias1 = bk; p.bias2 = bv; p.bias3 = bgcn;
  gemm_k<EP_QKVG,false><<<dim3(48,32,1), 256, 0, stream>>>(p);

  // scores: Q @ K^T /8 + geom-bias (batched b,h)  (M=N=768,K=64)
  p = GP{};
  p.A = qbf; p.lda = 512; p.aBatch = 768*512; p.aHead = 64;
  p.Bt = kbf; p.ldb = 512; p.bBatch = 768*512; p.bHead = 64;
  p.K = 64; p.zdiv = 8;
  p.outb = sbf; p.geom = geom; p.wg = Wg; p.bgv = bg; p.mask = mask;
  gemm_k<EP_SCORES,false><<<dim3(12,12,32), 256, 0, stream>>>(p);

  // softmax rows (in place)
  softmax_k<<<32*768, 256, 0, stream>>>(sbf);

  // PV: attn @ V  (M=768,N=64,K=768 per b,h)
  p = GP{};
  p.A = sbf; p.lda = 768; p.aBatch = (long)8*768*768; p.aHead = (long)768*768;
  p.Bt = vt; p.ldb = 768; p.bBatch = (long)512*768; p.bHead = (long)64*768;
  p.K = 768; p.zdiv = 8;
  p.outb = ctx;
  gemm_k<EP_CTX,false><<<dim3(12,1,32), 256, 0, stream>>>(p);

  // GCN: adj @ g with gelu  (M=768,N=512,K=768 per b)
  p = GP{};
  p.A = adjb; p.lda = 768; p.aBatch = (long)768*768; p.aHead = 0;
  p.Bt = gt; p.ldb = 768; p.bBatch = (long)512*768; p.bHead = 0;
  p.K = 768; p.zdiv = 1;
  p.outf = gcnr;
  gemm_k<EP_GCN,false><<<dim3(12,8,4), 256, 0, stream>>>(p);

  // attn_out = ctx @ Wo + bo  (M=3072,N=512,K=512)
  p = GP{};
  p.A = ctx; p.lda = 512; p.aBatch = 0; p.aHead = 0;
  p.Bt = woT; p.ldb = 512; p.bBatch = 0; p.bHead = 0;
  p.K = 512; p.zdiv = 1;
  p.outf = aout; p.bias0 = bo;
  gemm_k<EP_ATTNOUT,false><<<dim3(48,8,1), 256, 0, stream>>>(p);

  // residual + LN2
  resid_ln2_k<<<3072, 256, 0, stream>>>(x, aout, gcnr, gate, ln2s, ln2b, xmid, h2bf);

  // FFN1 dual: u,gate GEMMs + GLU  (M=3072,N=2048,K=512)
  p = GP{};
  p.A = h2bf; p.lda = 512; p.aBatch = 0; p.aHead = 0;
  p.Bt = w1T; p.ldb = 512; p.bBatch = 0; p.bHead = 0;
  p.Bt2 = w1T + (long)2048*512;
  p.K = 512; p.zdiv = 1;
  p.outb = act; p.bias0 = b1;
  gemm_k<EP_FF,true><<<dim3(48,32,1), 256, 0, stream>>>(p);

  // FFN2 + final residual  (M=3072,N=512,K=2048)
  p = GP{};
  p.A = act; p.lda = 2048; p.aBatch = 0; p.aHead = 0;
  p.Bt = w2T; p.ldb = 2048; p.bBatch = 0; p.bHead = 0;
  p.K = 2048; p.zdiv = 1;
  p.outf = out; p.bias0 = b2; p.addf = xmid;
  gemm_k<EP_FINAL,false><<<dim3(48,8,1), 256, 0, stream>>>(p);
}

// Round 5
// 313.656 us; speedup vs baseline: 1.1114x; 1.1114x over previous
//
#include <hip/hip_runtime.h>
#include <hip/hip_bf16.h>
#include <math.h>

typedef __attribute__((ext_vector_type(8))) short bf8;
typedef __attribute__((ext_vector_type(4))) float f4;

__device__ __forceinline__ ushort f2bf(float x){
  union { float f; unsigned u; } v; v.f = x;
  unsigned r = (v.u + 0x7fffu + ((v.u >> 16) & 1u)) >> 16;
  return (ushort)r;
}
__device__ __forceinline__ float bf2f(ushort b){
  union { unsigned u; float f; } v; v.u = ((unsigned)b) << 16;
  return v.f;
}

// ---------------- generic 64x64 tile bf16 MFMA GEMM ----------------
struct GP {
  const ushort* A; long lda; long aBatch; long aHead;
  const ushort* Bt; long ldb; long bBatch; long bHead;
  const ushort* Bt2;
  int K; int zdiv;
  float* outf; ushort* outb;
  ushort* o1; ushort* o2; ushort* o3;
  const float* bias0; const float* bias1; const float* bias2; const float* bias3;
  const float* addf;
};

enum { EP_QKVG=0, EP_GCN, EP_ATTNOUT, EP_FF, EP_FINAL };

template<int EPI, bool DUAL>
__global__ __launch_bounds__(256)
void gemm_k(GP p) {
  __shared__ __align__(16) ushort As[64*64];
  __shared__ __align__(16) ushort Bs[64*64];
  __shared__ __align__(16) ushort Bs2[DUAL ? 64*64 : 8];
  const int tid = threadIdx.x;
  const int lane = tid & 63, wave = tid >> 6;
  const int wm = wave >> 1, wn = wave & 1;
  const int bm = blockIdx.x, bn = blockIdx.y, z = blockIdx.z;
  const int zb = z / p.zdiv, zh = z % p.zdiv;
  const ushort* Ab  = p.A  + (long)zb*p.aBatch + (long)zh*p.aHead + (long)bm*64*p.lda;
  const ushort* Btb = p.Bt + (long)zb*p.bBatch + (long)zh*p.bHead + (long)bn*64*p.ldb;
  const ushort* Bt2b = DUAL ? (p.Bt2 + (long)bn*64*p.ldb) : (const ushort*)nullptr;

  f4 acc[2][2] = {};
  f4 acc2[2][2] = {};

  const int sr = tid >> 3, sc = tid & 7;
  const int g = lane >> 4, lr = lane & 15;

  for (int k0 = 0; k0 < p.K; k0 += 64) {
    #pragma unroll
    for (int i = 0; i < 2; ++i) {
      int row = sr + i*32;
      int sw = (sc ^ (row & 7)) * 8;
      *(uint4*)&As[row*64 + sw] = *(const uint4*)(Ab  + (long)row*p.lda + k0 + sc*8);
      *(uint4*)&Bs[row*64 + sw] = *(const uint4*)(Btb + (long)row*p.ldb + k0 + sc*8);
      if (DUAL)
        *(uint4*)&Bs2[row*64 + sw] = *(const uint4*)(Bt2b + (long)row*p.ldb + k0 + sc*8);
    }
    __syncthreads();
    #pragma unroll
    for (int kw = 0; kw < 2; ++kw) {
      bf8 af[2], bfr[2], bf2[2];
      int chunk = kw*4 + g;
      #pragma unroll
      for (int f = 0; f < 2; ++f) {
        int ar = wm*32 + f*16 + lr;
        af[f]  = *(const bf8*)&As[ar*64 + ((chunk ^ (ar & 7)) * 8)];
        int br = wn*32 + f*16 + lr;
        bfr[f] = *(const bf8*)&Bs[br*64 + ((chunk ^ (br & 7)) * 8)];
        if (DUAL) bf2[f] = *(const bf8*)&Bs2[br*64 + ((chunk ^ (br & 7)) * 8)];
      }
      #pragma unroll
      for (int fm = 0; fm < 2; ++fm)
        #pragma unroll
        for (int fn = 0; fn < 2; ++fn) {
          acc[fm][fn] = __builtin_amdgcn_mfma_f32_16x16x32_bf16(af[fm], bfr[fn], acc[fm][fn], 0,0,0);
          if (DUAL) acc2[fm][fn] = __builtin_amdgcn_mfma_f32_16x16x32_bf16(af[fm], bf2[fn], acc2[fm][fn], 0,0,0);
        }
    }
    __syncthreads();
  }

  #pragma unroll
  for (int fm = 0; fm < 2; ++fm)
  #pragma unroll
  for (int fn = 0; fn < 2; ++fn)
  #pragma unroll
  for (int i = 0; i < 4; ++i) {
    int grow = bm*64 + wm*32 + fm*16 + g*4 + i;
    int gcol = bn*64 + wn*32 + fn*16 + lr;
    float v = acc[fm][fn][i];
    if constexpr (EPI == EP_QKVG) {
      int sec = gcol >> 9, cc = gcol & 511;
      const float* bp = sec==0 ? p.bias0 : sec==1 ? p.bias1 : sec==2 ? p.bias2 : p.bias3;
      v += bp[cc];
      ushort bvv = f2bf(v);
      if (sec == 0)      p.outb[(long)grow*512 + cc] = bvv;
      else if (sec == 1) p.o1[(long)grow*512 + cc] = bvv;
      else {
        int b = grow / 768, l = grow - b*768;
        ushort* dst = (sec==2) ? p.o2 : p.o3;
        dst[((long)b*512 + cc)*768 + l] = bvv;
      }
    } else if constexpr (EPI == EP_GCN) {
      float ge = 0.5f * v * (1.f + erff(v * 0.70710678118f));
      p.outf[((long)z*768 + grow)*512 + gcol] = ge;
    } else if constexpr (EPI == EP_ATTNOUT) {
      p.outf[(long)grow*512 + gcol] = v + p.bias0[gcol];
    } else if constexpr (EPI == EP_FF) {
      float u = v + p.bias0[gcol];
      float gt = acc2[fm][fn][i] + p.bias0[2048 + gcol];
      float a = u / (1.f + expf(-gt));
      p.outb[(long)grow*2048 + gcol] = f2bf(a);
    } else if constexpr (EPI == EP_FINAL) {
      long idx = (long)grow*512 + gcol;
      p.outf[idx] = p.addf[idx] + v + p.bias0[gcol];
    }
  }
}

// -------- fused flash attention: scores(+bias) -> online softmax -> PV --------
// grid (12, 32): x = q-tile (64 rows), y = b*8+h. 256 threads = 4 waves.
__global__ __launch_bounds__(256) void flash_k(const ushort* __restrict__ qg,
    const ushort* __restrict__ kg, const ushort* __restrict__ vtg,
    const ushort* __restrict__ biasg, ushort* __restrict__ ctx) {
  __shared__ __align__(16) ushort Ks[64*64];
  __shared__ __align__(16) ushort Vs[64*64];
  __shared__ __align__(16) ushort Ps[64*64];
  const int tid = threadIdx.x;
  const int lane = tid & 63, w = tid >> 6;
  const int g = lane >> 4, lr = lane & 15;
  const int qt = blockIdx.x, bh = blockIdx.y;
  const int b = bh >> 3, h = bh & 7;
  const int q0 = qt*64;

  // Q fragments: wave w owns q rows q0+w*16 .. +16, all DK=64 (2 k-chunks of 32)
  bf8 aq[2];
  #pragma unroll
  for (int kk = 0; kk < 2; ++kk)
    aq[kk] = *(const bf8*)&qg[(long)(b*768 + q0 + w*16 + lr)*512 + h*64 + kk*32 + g*8];

  f4 o[4] = {};
  float mrow[4], lsum[4];
  #pragma unroll
  for (int i = 0; i < 4; ++i) { mrow[i] = -1e30f; lsum[i] = 0.f; }

  const int srow = tid >> 3, sc = tid & 7;

  for (int kt = 0; kt < 12; ++kt) {
    const int kbase = kt*64;
    #pragma unroll
    for (int ps = 0; ps < 2; ++ps) {
      int r = srow + ps*32;
      int sw = ((sc ^ (r & 7)) * 8);
      *(uint4*)&Ks[r*64 + sw] = *(const uint4*)&kg[(long)(b*768 + kbase + r)*512 + h*64 + sc*8];
      *(uint4*)&Vs[r*64 + sw] = *(const uint4*)&vtg[((long)b*512 + h*64 + r)*768 + kbase + sc*8];
    }
    __syncthreads();

    // S = Q K^T  (per wave: 16 q rows x 64 k cols)
    f4 s[4] = {};
    #pragma unroll
    for (int kn = 0; kn < 4; ++kn) {
      #pragma unroll
      for (int kk = 0; kk < 2; ++kk) {
        int row = kn*16 + lr;
        bf8 bk = *(const bf8*)&Ks[row*64 + (((kk*4+g) ^ (row & 7)) * 8)];
        s[kn] = __builtin_amdgcn_mfma_f32_16x16x32_bf16(aq[kk], bk, s[kn], 0,0,0);
      }
    }

    // + geometric bias (mask pre-folded), scale 1/sqrt(64)
    float pv[4][4];
    #pragma unroll
    for (int kn = 0; kn < 4; ++kn)
      #pragma unroll
      for (int i = 0; i < 4; ++i) {
        float bv = bf2f(biasg[((long)bh*768 + q0 + w*16 + g*4 + i)*768 + kbase + kn*16 + lr]);
        pv[kn][i] = s[kn][i]*0.125f + bv;
      }

    // online softmax update (rows live across lanes sharing l>>4 group)
    #pragma unroll
    for (int i = 0; i < 4; ++i) {
      float m2 = fmaxf(fmaxf(pv[0][i], pv[1][i]), fmaxf(pv[2][i], pv[3][i]));
      #pragma unroll
      for (int off = 1; off < 16; off <<= 1) m2 = fmaxf(m2, __shfl_xor(m2, off, 64));
      float mnew = fmaxf(mrow[i], m2);
      float scale = __expf(mrow[i] - mnew);
      mrow[i] = mnew;
      float psum = 0.f;
      #pragma unroll
      for (int kn = 0; kn < 4; ++kn) { pv[kn][i] = __expf(pv[kn][i] - mnew); psum += pv[kn][i]; }
      #pragma unroll
      for (int off = 1; off < 16; off <<= 1) psum += __shfl_xor(psum, off, 64);
      lsum[i] = lsum[i]*scale + psum;
      #pragma unroll
      for (int dn = 0; dn < 4; ++dn) o[dn][i] *= scale;
    }

    // write P into this wave's private 16-row LDS strip (same-wave RAW: no barrier)
    #pragma unroll
    for (int kn = 0; kn < 4; ++kn)
      #pragma unroll
      for (int i = 0; i < 4; ++i) {
        int row = w*16 + g*4 + i;
        int col = kn*16 + lr;
        Ps[row*64 + (((col >> 3) ^ (row & 7)) * 8) + (col & 7)] = f2bf(pv[kn][i]);
      }

    // O += P V
    #pragma unroll
    for (int kk2 = 0; kk2 < 2; ++kk2) {
      int prow = w*16 + lr;
      bf8 pa = *(const bf8*)&Ps[prow*64 + (((kk2*4+g) ^ (prow & 7)) * 8)];
      #pragma unroll
      for (int dn = 0; dn < 4; ++dn) {
        int vrow = dn*16 + lr;
        bf8 bv = *(const bf8*)&Vs[vrow*64 + (((kk2*4+g) ^ (vrow & 7)) * 8)];
        o[dn] = __builtin_amdgcn_mfma_f32_16x16x32_bf16(pa, bv, o[dn], 0,0,0);
      }
    }
    __syncthreads();
  }

  #pragma unroll
  for (int i = 0; i < 4; ++i) {
    float inv = 1.f / lsum[i];
    #pragma unroll
    for (int dn = 0; dn < 4; ++dn)
      ctx[(long)(b*768 + q0 + w*16 + g*4 + i)*512 + h*64 + dn*16 + lr] = f2bf(o[dn][i]*inv);
  }
}

// ---------------- transpose + fp32->bf16 convert: dst[C][R] = src[R][C] ----------------
__global__ __launch_bounds__(256) void transpose_bf(const float* src, ushort* dst, int R, int C) {
  __shared__ float t[32][33];
  int r0 = blockIdx.x*32, c0 = blockIdx.y*32;
  int tr = threadIdx.x >> 5, tc = threadIdx.x & 31;
  #pragma unroll
  for (int i = 0; i < 4; ++i)
    t[tr + i*8][tc] = src[(long)(r0 + tr + i*8)*C + c0 + tc];
  __syncthreads();
  #pragma unroll
  for (int i = 0; i < 4; ++i)
    dst[(long)(c0 + tr + i*8)*R + r0 + tc] = f2bf(t[tc][tr + i*8]);
}

// ---------------- LayerNorm (row=512) -> bf16 ----------------
__global__ __launch_bounds__(256) void ln_k(const float* x, const float* gam, const float* bet, ushort* out) {
  int row = blockIdx.x, tid = threadIdx.x;
  long base = (long)row*512;
  float v0 = x[base+tid], v1 = x[base+tid+256];
  float s = v0+v1, q = v0*v0 + v1*v1;
  #pragma unroll
  for (int off=32; off>=1; off>>=1){ s += __shfl_down(s,off,64); q += __shfl_down(q,off,64); }
  __shared__ float red[8];
  int lane=tid&63, wave=tid>>6;
  if (lane==0){ red[wave]=s; red[4+wave]=q; }
  __syncthreads();
  if (tid==0){ red[0]=red[0]+red[1]+red[2]+red[3]; red[4]=red[4]+red[5]+red[6]+red[7]; }
  __syncthreads();
  float mu = red[0]*(1.f/512.f);
  float var = red[4]*(1.f/512.f) - mu*mu;
  float rs = rsqrtf(var + 1e-5f);
  out[base+tid]     = f2bf((v0-mu)*rs*gam[tid]     + bet[tid]);
  out[base+tid+256] = f2bf((v1-mu)*rs*gam[tid+256] + bet[tid+256]);
}

// ---------------- residual + LayerNorm2 ----------------
__global__ __launch_bounds__(256) void resid_ln2_k(const float* x, const float* ao, const float* gc,
    const float* gatep, const float* gam, const float* bet, float* xmid, ushort* h2) {
  int row = blockIdx.x, tid = threadIdx.x;
  long base = (long)row*512;
  float gate = *gatep;
  float v0 = x[base+tid]     + ao[base+tid]     + gc[base+tid]*gate;
  float v1 = x[base+tid+256] + ao[base+tid+256] + gc[base+tid+256]*gate;
  xmid[base+tid] = v0; xmid[base+tid+256] = v1;
  float s = v0+v1, q = v0*v0 + v1*v1;
  #pragma unroll
  for (int off=32; off>=1; off>>=1){ s += __shfl_down(s,off,64); q += __shfl_down(q,off,64); }
  __shared__ float red[8];
  int lane=tid&63, wave=tid>>6;
  if (lane==0){ red[wave]=s; red[4+wave]=q; }
  __syncthreads();
  if (tid==0){ red[0]=red[0]+red[1]+red[2]+red[3]; red[4]=red[4]+red[5]+red[6]+red[7]; }
  __syncthreads();
  float mu = red[0]*(1.f/512.f);
  float var = red[4]*(1.f/512.f) - mu*mu;
  float rs = rsqrtf(var + 1e-5f);
  h2[base+tid]     = f2bf((v0-mu)*rs*gam[tid]     + bet[tid]);
  h2[base+tid+256] = f2bf((v1-mu)*rs*gam[tid+256] + bet[tid+256]);
}

// ------- fused single geom pass: adj (row-normalized) + 8-head score bias -------
// grid 3072 = (b,l); 256 threads; each thread handles m = tid + {0,256,512}
__global__ __launch_bounds__(256) void adjbias_k(const float* __restrict__ geom,
    const int* __restrict__ mask, const float* __restrict__ Wg, const float* __restrict__ bg,
    ushort* __restrict__ adjb, ushort* __restrict__ biasb) {
  int bl = blockIdx.x;
  int b = bl / 768, l = bl - b*768;
  int tid = threadIdx.x;
  __shared__ float wgs[56];
  __shared__ float bgs[8];
  if (tid < 56) wgs[tid] = Wg[tid];
  if (tid < 8)  bgs[tid] = bg[tid];
  __syncthreads();
  float ml = (float)mask[bl];
  float e[3]; float ssum = 0.f;
  #pragma unroll
  for (int j = 0; j < 3; ++j) {
    int m = tid + j*256;
    const float* gp = &geom[((long)bl*768 + m)*7];
    float g0 = gp[0], g1 = gp[1], g2 = gp[2], g3 = gp[3], g4 = gp[4], g5 = gp[5], g6 = gp[6];
    float mm = (float)mask[b*768 + m];
    e[j] = __expf(-g0*0.2f) * mm;
    ssum += e[j];
    #pragma unroll
    for (int hh = 0; hh < 8; ++hh) {
      float bv = bgs[hh] + g0*wgs[hh] + g1*wgs[8+hh] + g2*wgs[16+hh] + g3*wgs[24+hh]
               + g4*wgs[32+hh] + g5*wgs[40+hh] + g6*wgs[48+hh];
      biasb[((long)(b*8+hh)*768 + l)*768 + m] = f2bf(mm != 0.f ? bv : -10000.f);
    }
  }
  #pragma unroll
  for (int off=32; off>=1; off>>=1) ssum += __shfl_down(ssum, off, 64);
  __shared__ float red[4];
  int lane = tid & 63, wave = tid >> 6;
  if (lane == 0) red[wave] = ssum;
  __syncthreads();
  if (tid == 0) red[0] = red[0]+red[1]+red[2]+red[3];
  __syncthreads();
  float inv = ml / (ml*red[0] + 1e-6f);
  #pragma unroll
  for (int j = 0; j < 3; ++j)
    adjb[(long)bl*768 + tid + j*256] = f2bf(e[j] * inv);
}

extern "C" void kernel_launch(void* const* d_in, const int* in_sizes, int n_in,
                              void* d_out, int out_size, void* d_ws, size_t ws_size,
                              hipStream_t stream) {
  const float* x    = (const float*)d_in[0];
  const float* geom = (const float*)d_in[1];
  const int*   mask = (const int*)d_in[2];
  const float* Wq   = (const float*)d_in[3];
  const float* bq   = (const float*)d_in[4];
  const float* Wk   = (const float*)d_in[5];
  const float* bk   = (const float*)d_in[6];
  const float* Wv   = (const float*)d_in[7];
  const float* bv   = (const float*)d_in[8];
  const float* Wo   = (const float*)d_in[9];
  const float* bo   = (const float*)d_in[10];
  const float* Wg   = (const float*)d_in[11];
  const float* bg   = (const float*)d_in[12];
  const float* Wgcn = (const float*)d_in[13];
  const float* bgcn = (const float*)d_in[14];
  const float* gate = (const float*)d_in[15];
  const float* W1   = (const float*)d_in[16];
  const float* b1   = (const float*)d_in[17];
  const float* W2   = (const float*)d_in[18];
  const float* b2   = (const float*)d_in[19];
  const float* ln1s = (const float*)d_in[20];
  const float* ln1b = (const float*)d_in[21];
  const float* ln2s = (const float*)d_in[22];
  const float* ln2b = (const float*)d_in[23];
  float* out = (float*)d_out;

  char* wp = (char*)d_ws;
  auto alloc = [&](size_t bytes)->char* { char* r = wp; wp += (bytes + 255) & ~(size_t)255; return r; };
  ushort* wqkvgT = (ushort*)alloc(2048*512*2);
  ushort* woT    = (ushort*)alloc(512*512*2);
  ushort* w1T    = (ushort*)alloc(4096*512*2);
  ushort* w2T    = (ushort*)alloc(512*2048*2);
  ushort* hbf    = (ushort*)alloc(3072*512*2);
  ushort* qbf    = (ushort*)alloc(3072*512*2);
  ushort* kbf    = (ushort*)alloc(3072*512*2);
  ushort* vt     = (ushort*)alloc((size_t)4*512*768*2);
  ushort* gt     = (ushort*)alloc((size_t)4*512*768*2);
  ushort* adjb   = (ushort*)alloc((size_t)4*768*768*2);
  ushort* biasb  = (ushort*)alloc((size_t)32*768*768*2);
  ushort* ctx    = (ushort*)alloc(3072*512*2);
  float*  aout   = (float*)alloc(3072*512*4);
  float*  gcnr   = (float*)alloc(3072*512*4);
  float*  xmid   = (float*)alloc(3072*512*4);
  ushort* h2bf   = (ushort*)alloc(3072*512*2);
  ushort* act    = biasb;   // reuse: bias dead after flash_k, 12.6MB <= 37.7MB

  // weight transposes -> bf16
  transpose_bf<<<dim3(16,16), 256, 0, stream>>>(Wq,   wqkvgT + 0*512*512, 512, 512);
  transpose_bf<<<dim3(16,16), 256, 0, stream>>>(Wk,   wqkvgT + 1*512*512, 512, 512);
  transpose_bf<<<dim3(16,16), 256, 0, stream>>>(Wv,   wqkvgT + 2*512*512, 512, 512);
  transpose_bf<<<dim3(16,16), 256, 0, stream>>>(Wgcn, wqkvgT + 3*512*512, 512, 512);
  transpose_bf<<<dim3(16,16), 256, 0, stream>>>(Wo,   woT, 512, 512);
  transpose_bf<<<dim3(16,128),256, 0, stream>>>(W1,   w1T, 512, 4096);
  transpose_bf<<<dim3(64,16), 256, 0, stream>>>(W2,   w2T, 2048, 512);

  // LN1
  ln_k<<<3072, 256, 0, stream>>>(x, ln1s, ln1b, hbf);

  // fused adj + geometric bias (single 66MB geom pass)
  adjbias_k<<<3072, 256, 0, stream>>>(geom, mask, Wg, bg, adjb, biasb);

  GP p{};
  // GEMM1: h @ [Wq|Wk|Wv|Wgcn]  (M=3072,N=2048,K=512)
  p.A = hbf; p.lda = 512; p.aBatch = 0; p.aHead = 0;
  p.Bt = wqkvgT; p.ldb = 512; p.bBatch = 0; p.bHead = 0;
  p.K = 512; p.zdiv = 1;
  p.outb = qbf; p.o1 = kbf; p.o2 = vt; p.o3 = gt;
  p.bias0 = bq; p.bias1 = bk; p.bias2 = bv; p.bias3 = bgcn;
  gemm_k<EP_QKVG,false><<<dim3(48,32,1), 256, 0, stream>>>(p);

  // fused flash attention: scores+bias -> softmax -> PV
  flash_k<<<dim3(12,32), 256, 0, stream>>>(qbf, kbf, vt, biasb, ctx);

  // GCN: adj @ g with gelu  (M=768,N=512,K=768 per b)
  p = GP{};
  p.A = adjb; p.lda = 768; p.aBatch = (long)768*768; p.aHead = 0;
  p.Bt = gt; p.ldb = 768; p.bBatch = (long)512*768; p.bHead = 0;
  p.K = 768; p.zdiv = 1;
  p.outf = gcnr;
  gemm_k<EP_GCN,false><<<dim3(12,8,4), 256, 0, stream>>>(p);

  // attn_out = ctx @ Wo + bo  (M=3072,N=512,K=512)
  p = GP{};
  p.A = ctx; p.lda = 512; p.aBatch = 0; p.aHead = 0;
  p.Bt = woT; p.ldb = 512; p.bBatch = 0; p.bHead = 0;
  p.K = 512; p.zdiv = 1;
  p.outf = aout; p.bias0 = bo;
  gemm_k<EP_ATTNOUT,false><<<dim3(48,8,1), 256, 0, stream>>>(p);

  // residual + LN2
  resid_ln2_k<<<3072, 256, 0, stream>>>(x, aout, gcnr, gate, ln2s, ln2b, xmid, h2bf);

  // FFN1 dual: u,gate GEMMs + GLU  (M=3072,N=2048,K=512)
  p = GP{};
  p.A = h2bf; p.lda = 512; p.aBatch = 0; p.aHead = 0;
  p.Bt = w1T; p.ldb = 512; p.bBatch = 0; p.bHead = 0;
  p.Bt2 = w1T + (long)2048*512;
  p.K = 512; p.zdiv = 1;
  p.outb = act; p.bias0 = b1;
  gemm_k<EP_FF,true><<<dim3(48,32,1), 256, 0, stream>>>(p);

  // FFN2 + final residual  (M=3072,N=512,K=2048)
  p = GP{};
  p.A = act; p.lda = 2048; p.aBatch = 0; p.aHead = 0;
  p.Bt = w2T; p.ldb = 2048; p.bBatch = 0; p.bHead = 0;
  p.K = 2048; p.zdiv = 1;
  p.outf = out; p.bias0 = b2; p.addf = xmid;
  gemm_k<EP_FINAL,false><<<dim3(48,8,1), 256, 0, stream>>>(p);
}